// Round 4
// baseline (689.845 us; speedup 1.0000x reference)
//
#include <hip/hip_runtime.h>
#include <hip/hip_bf16.h>

// ---------------------------------------------------------------------------
// 2-layer GraphSAGE (mean aggr) on gfx950.
// R8 (this round): aggregation<->GEMM fusion. R5-R7 established sage_agg is
// at a ~3.9 TB/s L2-fill throughput ceiling (379 MB FETCH, flat across MLP
// 1/2/4 variants) -> stop tuning the gather; overlap it with MFMA instead.
// sage_fused: block owns 64 dst rows; phase 1 gathers neighbor x-halves and
// builds bf16 mean rows in LDS (XOR-swizzled); phase 2 runs the 64x256 GEMM
// with A = [LDS mean | staged global x]. Co-resident blocks overlap gather
// and MFMA; saves 100 MB/layer of mean write+read and 2 launches.
// Memory plan (no in-place races): layer1 xA1 -> xB (ws), layer2 xB -> d_out.
// Needs ~213 MB ws; runtime check falls back to the proven split pipeline.
// Also: node_hist_scan folds the 3 scan kernels into node_hist
// (offs = boff[bucket] + in-bucket 64-wide wave scan). 17 -> 11 launches.
// CSR build deterministic (R3). Gather loop structure from R6 (perf-equal
// to R4/R7 variants; ceiling-bound).
// ---------------------------------------------------------------------------

typedef __bf16 bf16x8 __attribute__((ext_vector_type(8)));
typedef __bf16 bf16x4 __attribute__((ext_vector_type(4)));
typedef float  f32x4  __attribute__((ext_vector_type(4)));
typedef float  f32x8  __attribute__((ext_vector_type(8)));

#define ROWB 1024   // bytes per A row: 512 bf16 (K = 512 = [mean | x])
#define NPART 256   // partition blocks
#define MAXBUK 2048 // bucket capacity bound (N<=131072)

__device__ __forceinline__ void async_copy16(void* lds_dst, const void* g_src) {
  __builtin_amdgcn_global_load_lds(
      (const __attribute__((address_space(1))) void*)g_src,
      (__attribute__((address_space(3))) void*)lds_dst, 16, 0, 0);
}

// ---- CSR build ------------------------------------------------------------

// block p: LDS histogram of dst>>6 over its chunk -> hmat[p][:]
__global__ void bin_count(const int* __restrict__ dst, int* __restrict__ hmat,
                          int E, int chunk, int nbuk) {
  __shared__ int lh[MAXBUK];
  int p = blockIdx.x, tid = threadIdx.x;
  for (int i = tid; i < nbuk; i += 256) lh[i] = 0;
  __syncthreads();
  int base = p * chunk, end = min(base + chunk, E);
  for (int e = base + tid; e < end; e += 256) atomicAdd(&lh[dst[e] >> 6], 1);
  __syncthreads();
  for (int i = tid; i < nbuk; i += 256) hmat[p * nbuk + i] = lh[i];
}

// block b: exclusive scan of hmat[0..NPART-1][b]; btot[b] = total
__global__ void col_scan(int* __restrict__ hmat, int* __restrict__ btot, int nbuk) {
  __shared__ int s[NPART];
  int b = blockIdx.x, t = threadIdx.x;  // NPART threads
  int v = hmat[t * nbuk + b];
  s[t] = v; __syncthreads();
  for (int d = 1; d < NPART; d <<= 1) {
    int add = (t >= d) ? s[t - d] : 0;
    __syncthreads();
    s[t] += add;
    __syncthreads();
  }
  hmat[t * nbuk + b] = s[t] - v;  // exclusive within bucket
  if (t == NPART - 1) btot[b] = s[t];
}

// single block, 1024 threads, nb <= 2048: exclusive scan btot -> boff
__global__ void bucket_scan(const int* __restrict__ btot, int* __restrict__ boff, int nb) {
  __shared__ int s[2048];
  int t = threadIdx.x;
  for (int i = t; i < 2048; i += 1024) s[i] = (i < nb) ? btot[i] : 0;
  __syncthreads();
  for (int d = 1; d < 2048; d <<= 1) {
    int v0 = (t >= d) ? s[t - d] : 0;
    int v1 = (t + 1024 >= d) ? s[t + 1024 - d] : 0;
    __syncthreads();
    s[t] += v0; s[t + 1024] += v1;
    __syncthreads();
  }
  for (int i = t; i < nb; i += 1024) boff[i] = s[i] - btot[i];
}

// block p: write its chunk's edges into disjoint per-bucket windows.
// entry = src | ((dst&63) << 18)   (src < 2^18)
__global__ void part_write(const int* __restrict__ src, const int* __restrict__ dst,
                           const int* __restrict__ hmat, const int* __restrict__ boff,
                           int* __restrict__ ebuf, int E, int chunk, int nbuk) {
  __shared__ int cur[MAXBUK];
  int p = blockIdx.x, tid = threadIdx.x;
  for (int i = tid; i < nbuk; i += 256) cur[i] = hmat[p * nbuk + i] + boff[i];
  __syncthreads();
  int base = p * chunk, end = min(base + chunk, E);
  for (int e = base + tid; e < end; e += 256) {
    int d = dst[e];
    int pos = atomicAdd(&cur[d >> 6], 1);  // LDS atomic, low contention
    ebuf[pos] = src[e] | ((d & 63) << 18);
  }
}

// block b: degree histogram of its 64 nodes + in-bucket exclusive scan ->
// cnt[node], offs[node] = boff[b] + scan. Replaces node_hist + 3 scan kernels.
__global__ void node_hist_scan(const int* __restrict__ ebuf, const int* __restrict__ boff,
                               const int* __restrict__ btot, int* __restrict__ cnt,
                               int* __restrict__ offs, int N) {
  __shared__ int lh[64];
  int b = blockIdx.x, tid = threadIdx.x;
  if (tid < 64) lh[tid] = 0;
  __syncthreads();
  int s0 = boff[b], s1 = s0 + btot[b];
  for (int i = s0 + tid; i < s1; i += 256) atomicAdd(&lh[ebuf[i] >> 18], 1);
  __syncthreads();
  if (tid < 64) {  // wave 0: 64-wide inclusive shfl scan
    int v = lh[tid];
    int x = v;
#pragma unroll
    for (int d = 1; d < 64; d <<= 1) {
      int y = __shfl_up(x, d);
      if (tid >= d) x += y;
    }
    int node = b * 64 + tid;
    if (node < N) { cnt[node] = v; offs[node] = s0 + x - v; }
  }
}

// block b: place its bucket's edges into csr via LDS cursors (4KB window)
__global__ void csr_write(const int* __restrict__ ebuf, const int* __restrict__ boff,
                          const int* __restrict__ btot, const int* __restrict__ offs,
                          int* __restrict__ csr, int N) {
  __shared__ int cur[64];
  int b = blockIdx.x, tid = threadIdx.x;
  int node = b * 64 + tid;
  if (tid < 64) cur[tid] = (node < N) ? offs[node] : 0;
  __syncthreads();
  int s0 = boff[b], s1 = s0 + btot[b];
  for (int i = s0 + tid; i < s1; i += 256) {
    int e = ebuf[i];
    int p = atomicAdd(&cur[e >> 18], 1);
    csr[p] = e & 0x3FFFF;
  }
}

// ---- feature prep ---------------------------------------------------------

// Wt[n][k] = bf16( k<256 ? Wl[k][n] : Wr[k-256][n] ), row-major [256][512]
__global__ void prep_w_kernel(const float* __restrict__ W1l, const float* __restrict__ W1r,
                              const float* __restrict__ W2l, const float* __restrict__ W2r,
                              __bf16* __restrict__ Wt1, __bf16* __restrict__ Wt2) {
  int idx = blockIdx.x * 256 + threadIdx.x;  // 0 .. 2*131072-1
  int which = idx >> 17;
  int j = idx & 131071;
  int n = j >> 9, k = j & 511;
  const float* Wl = which ? W2l : W1l;
  const float* Wr = which ? W2r : W1r;
  float v = (k < 256) ? Wl[k * 256 + n] : Wr[(k - 256) * 256 + n];
  (which ? Wt2 : Wt1)[j] = (__bf16)v;
}

// x-half gather: xbase points at (row stride ROWB) destination of the x slot
__global__ void gather_x_kernel(const float* __restrict__ emb, const int* __restrict__ x_idx,
                                char* __restrict__ xbase, int N) {
  int wave = threadIdx.x >> 6, lane = threadIdx.x & 63;
  int i = blockIdx.x * 4 + wave;
  if (i >= N) return;
  int s = x_idx[i];
  float4 v = *(const float4*)(emb + (size_t)s * 256 + lane * 4);
  bf16x4 o = { (__bf16)v.x, (__bf16)v.y, (__bf16)v.z, (__bf16)v.w };
  *(bf16x4*)(xbase + (size_t)i * ROWB + lane * 8) = o;
}

// ---- FUSED aggregation + GEMM --------------------------------------------
// Block = 64 dst rows, 512 threads = 8 waves.
// Phase 1: each wave gathers/means 8 nodes (two 32-lane halves read different
// src rows at 16B/lane), writes bf16 mean rows into LDS meanbuf (XOR-swizzle
// (n&7)<<4 on the within-row byte offset -> conflict-free phase-2 reads).
// Phase 2: GEMM out[64,256] = [mean | x] @ Wt + bias. K 0..255 A-frags from
// meanbuf; K 256..511 A-frags double-buffer-staged from global x-halves.
// B (Wt) double-buffer-staged every kk. First B tile prefetched under phase 1.

template <int OUT_F32>
__global__ __launch_bounds__(512) void sage_fused(
    const char* __restrict__ Abase,   // rows: x-half bf16 at +512
    const __bf16* __restrict__ Wt,    // [256][512] bf16
    const float* __restrict__ bias,
    char* __restrict__ outbase,       // OUT_F32: fp32 rows (1KB); else bf16 at +512
    const int* __restrict__ csr, const int* __restrict__ cnt,
    const int* __restrict__ offs, int M) {
  __shared__ __align__(16) char lds[73728];  // mean 32K | B 2x16K | Ax 2x4K
  char* meanbuf = lds;
  char* Bbuf    = lds + 32768;
  char* Axbuf   = lds + 65536;
  const int tid = threadIdx.x;
  const int wave = tid >> 6, lane = tid & 63;
  const int r = lane & 15, q = lane >> 4;
  const int row0 = blockIdx.x * 64;

  auto stageB = [&](int kk, int buf) {
    char* bb = Bbuf + buf * 16384;
#pragma unroll
    for (int i2 = 0; i2 < 2; ++i2) {
      int h = wave * 2 + i2;  // 0..15
      async_copy16(bb + h * 1024 + lane * 16,
                   (const char*)Wt + ((size_t)(h * 16 + r) * 512 + kk * 32 + q * 8) * 2);
    }
  };
  auto stageA = [&](int kk, int buf) {  // kk in 8..15: x-half columns
    if (wave < 4) {
      char* ab = Axbuf + buf * 4096;
      int rowA = row0 + wave * 16 + r;
      rowA = rowA < M ? rowA : M - 1;  // clamp: garbage rows masked at store
      async_copy16(ab + wave * 1024 + lane * 16,
                   Abase + (size_t)rowA * ROWB + (size_t)(kk * 32 + q * 8) * 2);
    }
  };

  stageB(0, 0);  // prefetch first B tile; overlaps the whole gather phase

  // ---- phase 1: gather + mean -> meanbuf ----
  {
    int half = lane >> 5, l5 = lane & 31;
    const char* sb = Abase + 512 + l5 * 16;
    for (int s = 0; s < 8; ++s) {
      int i = row0 + wave * 8 + s;
      int ii = i < M ? i : M - 1;  // tail rows recompute M-1's mean (masked later)
      int deg = cnt[ii];
      const int* lp = csr + offs[ii];
      f32x8 acc = (f32x8)0.f;
      int g8 = deg >> 3;
      for (int t = 0; t < g8; ++t) {  // 8 edges/iter, 4 per half
        const int* p = lp + t * 8 + half;
        int s0 = p[0], s1 = p[2], s2 = p[4], s3 = p[6];
        bf16x8 v0 = *(const bf16x8*)(sb + (size_t)s0 * ROWB);
        bf16x8 v1 = *(const bf16x8*)(sb + (size_t)s1 * ROWB);
        bf16x8 v2 = *(const bf16x8*)(sb + (size_t)s2 * ROWB);
        bf16x8 v3 = *(const bf16x8*)(sb + (size_t)s3 * ROWB);
#pragma unroll
        for (int k = 0; k < 8; ++k)
          acc[k] += ((float)v0[k] + (float)v1[k]) + ((float)v2[k] + (float)v3[k]);
      }
      int base = g8 * 8;
      int rem = deg & 7;
      int rp = rem >> 1;
      for (int u = 0; u < rp; ++u) {
        int r0 = lp[base + 2 * u + half];
        bf16x8 v0 = *(const bf16x8*)(sb + (size_t)r0 * ROWB);
#pragma unroll
        for (int k = 0; k < 8; ++k) acc[k] += (float)v0[k];
      }
      if ((rem & 1) && half == 0) {
        int r0 = lp[deg - 1];
        bf16x8 v0 = *(const bf16x8*)(sb + (size_t)r0 * ROWB);
#pragma unroll
        for (int k = 0; k < 8; ++k) acc[k] += (float)v0[k];
      }
      float inv = 1.0f / (float)(deg > 0 ? deg : 1);
      bf16x8 o;
#pragma unroll
      for (int k = 0; k < 8; ++k) {
        float sv = acc[k] + __shfl_down(acc[k], 32);
        o[k] = (__bf16)(sv * inv);
      }
      if (half == 0) {
        int n = wave * 8 + s;  // row inside block
        *(bf16x8*)(meanbuf + n * 512 + ((l5 * 16) ^ ((n & 7) << 4))) = o;
      }
    }
  }
  __syncthreads();  // meanbuf visible; B(0) staging drained

  // ---- phase 2: GEMM ----
  const int wm = wave >> 1, wn = wave & 1;  // 4x2 wave grid, tile 16x128
  f32x4 acc[8];
#pragma unroll
  for (int u = 0; u < 8; ++u) acc[u] = (f32x4)0.f;

  for (int kk = 0; kk < 16; ++kk) {
    if (kk) __syncthreads();
    if (kk < 15) {
      stageB(kk + 1, (kk + 1) & 1);
      if (kk + 1 >= 8) stageA(kk + 1, (kk + 1) & 1);
    }
    bf16x8 a0;
    if (kk < 8) {
      int arow = wm * 16 + r;
      a0 = *(const bf16x8*)(meanbuf + arow * 512 +
                            ((kk * 64 + q * 16) ^ ((arow & 7) << 4)));
    } else {
      const char* ab = Axbuf + (kk & 1) * 4096;
      a0 = *(const bf16x8*)(ab + wm * 1024 + lane * 16);
    }
    const char* bb = Bbuf + (kk & 1) * 16384;
#pragma unroll
    for (int u = 0; u < 8; ++u) {
      bf16x8 b = *(const bf16x8*)(bb + (wn * 8 + u) * 1024 + lane * 16);
      acc[u] = __builtin_amdgcn_mfma_f32_16x16x32_bf16(a0, b, acc[u], 0, 0, 0);
    }
  }

  // epilogue: disjoint output buffer -> no in-place hazard
  int rbase = row0 + wm * 16 + q * 4;
#pragma unroll
  for (int u = 0; u < 8; ++u) {
    int col = wn * 128 + u * 16 + r;
    float bv = bias[col];
#pragma unroll
    for (int j = 0; j < 4; ++j) {
      int row = rbase + j;
      if (row < M) {
        float v = acc[u][j] + bv;
        if (OUT_F32)
          *(float*)(outbase + (size_t)row * ROWB + col * 4) = v;
        else
          *(__bf16*)(outbase + (size_t)row * ROWB + 512 + col * 2) = (__bf16)v;
      }
    }
  }
}

// ---- fallback split pipeline (used when ws too small) ---------------------

__global__ void sage_agg(const char* __restrict__ srcbase, char* __restrict__ dstbase,
                         const int* __restrict__ csr, const int* __restrict__ cnt,
                         const int* __restrict__ offs, int N) {
  int wave = threadIdx.x >> 6, lane = threadIdx.x & 63;
  int i = blockIdx.x * 4 + wave;
  if (i >= N) return;
  int deg = cnt[i];
  const int* lp = csr + offs[i];
  int half = lane >> 5, l5 = lane & 31;
  const char* sb = srcbase + l5 * 16;
  f32x8 acc = (f32x8)0.f;
  int g8 = deg >> 3;
  for (int t = 0; t < g8; ++t) {
    const int* p = lp + t * 8 + half;
    int s0 = p[0], s1 = p[2], s2 = p[4], s3 = p[6];
    bf16x8 v0 = *(const bf16x8*)(sb + (size_t)s0 * ROWB);
    bf16x8 v1 = *(const bf16x8*)(sb + (size_t)s1 * ROWB);
    bf16x8 v2 = *(const bf16x8*)(sb + (size_t)s2 * ROWB);
    bf16x8 v3 = *(const bf16x8*)(sb + (size_t)s3 * ROWB);
#pragma unroll
    for (int k = 0; k < 8; ++k)
      acc[k] += ((float)v0[k] + (float)v1[k]) + ((float)v2[k] + (float)v3[k]);
  }
  int base = g8 * 8;
  int rem = deg & 7;
  int rp = rem >> 1;
  for (int u = 0; u < rp; ++u) {
    int r0 = lp[base + 2 * u + half];
    bf16x8 v0 = *(const bf16x8*)(sb + (size_t)r0 * ROWB);
#pragma unroll
    for (int k = 0; k < 8; ++k) acc[k] += (float)v0[k];
  }
  if ((rem & 1) && half == 0) {
    int r0 = lp[deg - 1];
    bf16x8 v0 = *(const bf16x8*)(sb + (size_t)r0 * ROWB);
#pragma unroll
    for (int k = 0; k < 8; ++k) acc[k] += (float)v0[k];
  }
  float inv = 1.0f / (float)(deg > 0 ? deg : 1);
  bf16x8 o;
#pragma unroll
  for (int k = 0; k < 8; ++k) {
    float s = acc[k] + __shfl_down(acc[k], 32);
    o[k] = (__bf16)(s * inv);
  }
  if (half == 0)
    *(bf16x8*)(dstbase + (size_t)i * ROWB + l5 * 16) = o;
}

template <int OUT_F32>
__global__ __launch_bounds__(256) void gemm_sage(const char* __restrict__ Abase,
                                                 const __bf16* __restrict__ Wt,
                                                 const float* __restrict__ bias,
                                                 char* __restrict__ outbase, int M) {
  __shared__ __align__(16) char lds[40960];
  const int tid = threadIdx.x;
  const int wave = tid >> 6, lane = tid & 63;
  const int r = lane & 15, q = lane >> 4;
  const int wm = wave >> 1, wn = wave & 1;
  const int row0 = blockIdx.x * 64;
  f32x4 acc[2][8];
#pragma unroll
  for (int t = 0; t < 2; ++t)
#pragma unroll
    for (int u = 0; u < 8; ++u) acc[t][u] = (f32x4)0.f;
  auto stage = [&](int kk, int buf) {
    char* lbase = lds + buf * 20480;
    int rowA = row0 + wave * 16 + r;
    rowA = rowA < M ? rowA : M - 1;
    async_copy16(lbase + wave * 1024 + lane * 16,
                 Abase + (size_t)rowA * ROWB + (size_t)(kk * 32 + q * 8) * 2);
#pragma unroll
    for (int i = 0; i < 4; ++i) {
      int h = wave * 4 + i;
      async_copy16(lbase + 4096 + h * 1024 + lane * 16,
                   (const char*)Wt + ((size_t)(h * 16 + r) * 512 + kk * 32 + q * 8) * 2);
    }
  };
  stage(0, 0);
  for (int kk = 0; kk < 16; ++kk) {
    __syncthreads();
    if (kk < 15) stage(kk + 1, (kk + 1) & 1);
    const char* lbase = lds + (kk & 1) * 20480;
    bf16x8 a0 = *(const bf16x8*)(lbase + (wm * 2 + 0) * 1024 + lane * 16);
    bf16x8 a1 = *(const bf16x8*)(lbase + (wm * 2 + 1) * 1024 + lane * 16);
#pragma unroll
    for (int u = 0; u < 8; ++u) {
      bf16x8 b = *(const bf16x8*)(lbase + 4096 + (wn * 8 + u) * 1024 + lane * 16);
      acc[0][u] = __builtin_amdgcn_mfma_f32_16x16x32_bf16(a0, b, acc[0][u], 0, 0, 0);
      acc[1][u] = __builtin_amdgcn_mfma_f32_16x16x32_bf16(a1, b, acc[1][u], 0, 0, 0);
    }
  }
#pragma unroll
  for (int t = 0; t < 2; ++t) {
    int rbase = row0 + wm * 32 + t * 16 + q * 4;
#pragma unroll
    for (int u = 0; u < 8; ++u) {
      int col = wn * 128 + u * 16 + r;
      float bv = bias[col];
#pragma unroll
      for (int j = 0; j < 4; ++j) {
        int row = rbase + j;
        if (row < M) {
          float v = acc[t][u][j] + bv;
          if (OUT_F32)
            *(float*)(outbase + (size_t)row * ROWB + col * 4) = v;
          else
            *(__bf16*)(outbase + (size_t)row * ROWB + 512 + col * 2) = (__bf16)v;
        }
      }
    }
  }
}

// ---- final index gathers --------------------------------------------------

__global__ void gather_out_kernel(const float* __restrict__ x2, const int* __restrict__ drug,
                                  const int* __restrict__ se, float* __restrict__ out,
                                  int nd, int ns) {
  int wave = threadIdx.x >> 6, lane = threadIdx.x & 63;
  int ro = blockIdx.x * 4 + wave;
  if (ro >= nd + ns) return;
  int node = (ro < nd) ? drug[ro] : se[ro - nd];
  float4 v = *(const float4*)(x2 + (size_t)node * 256 + lane * 4);
  *(float4*)(out + (size_t)ro * 256 + lane * 4) = v;
}

// ---------------------------------------------------------------------------

extern "C" void kernel_launch(void* const* d_in, const int* in_sizes, int n_in,
                              void* d_out, int out_size, void* d_ws, size_t ws_size,
                              hipStream_t stream) {
  const float* emb  = (const float*)d_in[0];
  const float* W1l  = (const float*)d_in[1];
  const float* b1l  = (const float*)d_in[2];
  const float* W1r  = (const float*)d_in[3];
  const float* W2l  = (const float*)d_in[4];
  const float* b2l  = (const float*)d_in[5];
  const float* W2r  = (const float*)d_in[6];
  const int* x_idx  = (const int*)d_in[7];
  const int* edge   = (const int*)d_in[8];
  const int* drug   = (const int*)d_in[9];
  const int* se     = (const int*)d_in[10];

  const int N = in_sizes[7];       // 100000
  const int E = in_sizes[8] / 2;   // 1600000
  const int nd = in_sizes[9], ns = in_sizes[10];
  const int* esrc = edge;
  const int* edst = edge + E;
  const int NBUK = (N + 63) >> 6;  // 1563 (<= MAXBUK)
  const int chunk = (E + NPART - 1) / NPART;

  const size_t XPAD = (size_t)((N + 127) & ~127) * ROWB;   // ~102.5 MB
  const size_t NAL  = ((size_t)N * 4 + 255) & ~(size_t)255;
  const size_t EAL  = ((size_t)E * 4 + 255) & ~(size_t)255;
  const size_t need_fused = 2 * XPAD + 2 * (512 * 256 * 2) + 2 * NAL + EAL;
  const bool fused = (ws_size >= need_fused);

  // workspace carve
  char* ws = (char*)d_ws;
  size_t off = 0;
  char* xA1 = ws;                       off += XPAD;
  char* xB  = ws + off;                 if (fused) off += XPAD;  // fused layer-1 out
  __bf16* Wt1 = (__bf16*)(ws + off);    off += 512 * 256 * 2;
  __bf16* Wt2 = (__bf16*)(ws + off);    off += 512 * 256 * 2;
  int* cnt  = (int*)(ws + off);         off += NAL;
  int* offs = (int*)(ws + off);         off += NAL;
  int* csr  = (int*)(ws + off);         off += EAL;
  // transient arrays overlay xA1 (all dead before gather_x writes xA1):
  int* ebuf = (int*)xA1;                         // E ints (6.4 MB)
  int* hmat = (int*)(xA1 + (8u << 20));          // NPART*NBUK ints (~1.6 MB)
  int* btot = (int*)(xA1 + (16u << 20));         // NBUK ints
  int* boff = (int*)(xA1 + (16u << 20) + 16384); // NBUK ints

  // d_out carve: [drug nd*256 | se ns*256 | x2 N*256] fp32
  float* outp = (float*)d_out;
  float* x2 = outp + (size_t)(nd + ns) * 256;
  char* scratch2 = (char*)x2;  // fallback only: [mean2 bf16 | x1 bf16] -> x2 fp32

  const int QB = (N + 3) / 4;
  const int GB = (N + 63) / 64;

  prep_w_kernel<<<(2 * 131072) / 256, 256, 0, stream>>>(W1l, W1r, W2l, W2r, Wt1, Wt2);

  // CSR build, deterministic (no global atomics)
  bin_count<<<NPART, 256, 0, stream>>>(edst, hmat, E, chunk, NBUK);
  col_scan<<<NBUK, NPART, 0, stream>>>(hmat, btot, NBUK);
  bucket_scan<<<1, 1024, 0, stream>>>(btot, boff, NBUK);
  part_write<<<NPART, 256, 0, stream>>>(esrc, edst, hmat, boff, ebuf, E, chunk, NBUK);
  node_hist_scan<<<NBUK, 256, 0, stream>>>(ebuf, boff, btot, cnt, offs, N);
  csr_write<<<NBUK, 256, 0, stream>>>(ebuf, boff, btot, offs, csr, N);

  gather_x_kernel<<<QB, 256, 0, stream>>>(emb, x_idx, xA1 + 512, N);

  if (fused) {
    // layer 1: reads xA1 (x0), writes x1 bf16 into xB x-halves (disjoint)
    sage_fused<0><<<GB, 512, 0, stream>>>(xA1, Wt1, b1l, xB, csr, cnt, offs, N);
    // layer 2: reads xB (x1), writes x2 fp32 into d_out (disjoint)
    sage_fused<1><<<GB, 512, 0, stream>>>(xB, Wt2, b2l, (char*)x2, csr, cnt, offs, N);
  } else {
    // proven split pipeline (in-place epilogue safe: reads drained at barrier)
    sage_agg<<<QB, 256, 0, stream>>>(xA1 + 512, xA1, csr, cnt, offs, N);
    gemm_sage<0><<<GB, 256, 0, stream>>>(xA1, Wt1, b1l, scratch2, N);
    sage_agg<<<QB, 256, 0, stream>>>(scratch2 + 512, scratch2, csr, cnt, offs, N);
    gemm_sage<1><<<GB, 256, 0, stream>>>(scratch2, Wt2, b2l, scratch2, N);
  }

  gather_out_kernel<<<(nd + ns + 3) / 4, 256, 0, stream>>>(x2, drug, se, outp, nd, ns);
}

// Round 5
// 641.015 us; speedup vs baseline: 1.0762x; 1.0762x over previous
//
#include <hip/hip_runtime.h>
#include <hip/hip_bf16.h>

// ---------------------------------------------------------------------------
// 2-layer GraphSAGE (mean aggr) on gfx950.
// R9 (this round): revert R8 fusion (fused=215us/layer vs split 111+94;
// 2 blocks/CU starved the gather's TLP -> BW 3.9->2.4 TB/s). Keep
// node_hist_scan fusion. NEW: gemm_sage BM=128, wave tile 64x128 (acc[4][8],
// 4 waves): halves LDS reads per MFMA (12 ds_read vs 32 MFMA per wave-kk,
// was 10 vs 16) -> MFMA-limited instead of LDS-bound. Predict G 94->~55us.
// R5-R7: sage_agg is at a ~3.9 TB/s L2-fill throughput ceiling (379 MB
// FETCH, flat across MLP 1/2/4) -> left as the proven R6 form.
// CSR build deterministic (R3): bin_count -> col_scan -> bucket_scan ->
// part_write -> node_hist_scan -> csr_write. No contended global atomics.
// ---------------------------------------------------------------------------

typedef __bf16 bf16x8 __attribute__((ext_vector_type(8)));
typedef __bf16 bf16x4 __attribute__((ext_vector_type(4)));
typedef float  f32x4  __attribute__((ext_vector_type(4)));
typedef float  f32x8  __attribute__((ext_vector_type(8)));

#define ROWB 1024   // bytes per A row: 512 bf16 (K = 512 = [mean | x])
#define NPART 256   // partition blocks
#define MAXBUK 2048 // bucket capacity bound (N<=131072)

__device__ __forceinline__ void async_copy16(void* lds_dst, const void* g_src) {
  __builtin_amdgcn_global_load_lds(
      (const __attribute__((address_space(1))) void*)g_src,
      (__attribute__((address_space(3))) void*)lds_dst, 16, 0, 0);
}

// ---- CSR build ------------------------------------------------------------

// block p: LDS histogram of dst>>6 over its chunk -> hmat[p][:]
__global__ void bin_count(const int* __restrict__ dst, int* __restrict__ hmat,
                          int E, int chunk, int nbuk) {
  __shared__ int lh[MAXBUK];
  int p = blockIdx.x, tid = threadIdx.x;
  for (int i = tid; i < nbuk; i += 256) lh[i] = 0;
  __syncthreads();
  int base = p * chunk, end = min(base + chunk, E);
  for (int e = base + tid; e < end; e += 256) atomicAdd(&lh[dst[e] >> 6], 1);
  __syncthreads();
  for (int i = tid; i < nbuk; i += 256) hmat[p * nbuk + i] = lh[i];
}

// block b: exclusive scan of hmat[0..NPART-1][b]; btot[b] = total
__global__ void col_scan(int* __restrict__ hmat, int* __restrict__ btot, int nbuk) {
  __shared__ int s[NPART];
  int b = blockIdx.x, t = threadIdx.x;  // NPART threads
  int v = hmat[t * nbuk + b];
  s[t] = v; __syncthreads();
  for (int d = 1; d < NPART; d <<= 1) {
    int add = (t >= d) ? s[t - d] : 0;
    __syncthreads();
    s[t] += add;
    __syncthreads();
  }
  hmat[t * nbuk + b] = s[t] - v;  // exclusive within bucket
  if (t == NPART - 1) btot[b] = s[t];
}

// single block, 1024 threads, nb <= 2048: exclusive scan btot -> boff
__global__ void bucket_scan(const int* __restrict__ btot, int* __restrict__ boff, int nb) {
  __shared__ int s[2048];
  int t = threadIdx.x;
  for (int i = t; i < 2048; i += 1024) s[i] = (i < nb) ? btot[i] : 0;
  __syncthreads();
  for (int d = 1; d < 2048; d <<= 1) {
    int v0 = (t >= d) ? s[t - d] : 0;
    int v1 = (t + 1024 >= d) ? s[t + 1024 - d] : 0;
    __syncthreads();
    s[t] += v0; s[t + 1024] += v1;
    __syncthreads();
  }
  for (int i = t; i < nb; i += 1024) boff[i] = s[i] - btot[i];
}

// block p: write its chunk's edges into disjoint per-bucket windows.
// entry = src | ((dst&63) << 18)   (src < 2^18)
__global__ void part_write(const int* __restrict__ src, const int* __restrict__ dst,
                           const int* __restrict__ hmat, const int* __restrict__ boff,
                           int* __restrict__ ebuf, int E, int chunk, int nbuk) {
  __shared__ int cur[MAXBUK];
  int p = blockIdx.x, tid = threadIdx.x;
  for (int i = tid; i < nbuk; i += 256) cur[i] = hmat[p * nbuk + i] + boff[i];
  __syncthreads();
  int base = p * chunk, end = min(base + chunk, E);
  for (int e = base + tid; e < end; e += 256) {
    int d = dst[e];
    int pos = atomicAdd(&cur[d >> 6], 1);  // LDS atomic, low contention
    ebuf[pos] = src[e] | ((d & 63) << 18);
  }
}

// block b: degree histogram of its 64 nodes + in-bucket exclusive scan ->
// cnt[node], offs[node] = boff[b] + scan. Replaces node_hist + 3 scan kernels.
__global__ void node_hist_scan(const int* __restrict__ ebuf, const int* __restrict__ boff,
                               const int* __restrict__ btot, int* __restrict__ cnt,
                               int* __restrict__ offs, int N) {
  __shared__ int lh[64];
  int b = blockIdx.x, tid = threadIdx.x;
  if (tid < 64) lh[tid] = 0;
  __syncthreads();
  int s0 = boff[b], s1 = s0 + btot[b];
  for (int i = s0 + tid; i < s1; i += 256) atomicAdd(&lh[ebuf[i] >> 18], 1);
  __syncthreads();
  if (tid < 64) {  // wave 0: 64-wide inclusive shfl scan
    int v = lh[tid];
    int x = v;
#pragma unroll
    for (int d = 1; d < 64; d <<= 1) {
      int y = __shfl_up(x, d);
      if (tid >= d) x += y;
    }
    int node = b * 64 + tid;
    if (node < N) { cnt[node] = v; offs[node] = s0 + x - v; }
  }
}

// block b: place its bucket's edges into csr via LDS cursors (4KB window)
__global__ void csr_write(const int* __restrict__ ebuf, const int* __restrict__ boff,
                          const int* __restrict__ btot, const int* __restrict__ offs,
                          int* __restrict__ csr, int N) {
  __shared__ int cur[64];
  int b = blockIdx.x, tid = threadIdx.x;
  int node = b * 64 + tid;
  if (tid < 64) cur[tid] = (node < N) ? offs[node] : 0;
  __syncthreads();
  int s0 = boff[b], s1 = s0 + btot[b];
  for (int i = s0 + tid; i < s1; i += 256) {
    int e = ebuf[i];
    int p = atomicAdd(&cur[e >> 18], 1);
    csr[p] = e & 0x3FFFF;
  }
}

// ---- feature prep ---------------------------------------------------------

// Wt[n][k] = bf16( k<256 ? Wl[k][n] : Wr[k-256][n] ), row-major [256][512]
__global__ void prep_w_kernel(const float* __restrict__ W1l, const float* __restrict__ W1r,
                              const float* __restrict__ W2l, const float* __restrict__ W2r,
                              __bf16* __restrict__ Wt1, __bf16* __restrict__ Wt2) {
  int idx = blockIdx.x * 256 + threadIdx.x;  // 0 .. 2*131072-1
  int which = idx >> 17;
  int j = idx & 131071;
  int n = j >> 9, k = j & 511;
  const float* Wl = which ? W2l : W1l;
  const float* Wr = which ? W2r : W1r;
  float v = (k < 256) ? Wl[k * 256 + n] : Wr[(k - 256) * 256 + n];
  (which ? Wt2 : Wt1)[j] = (__bf16)v;
}

// x-half gather: xbase points at (row stride ROWB) destination of the x slot
__global__ void gather_x_kernel(const float* __restrict__ emb, const int* __restrict__ x_idx,
                                char* __restrict__ xbase, int N) {
  int wave = threadIdx.x >> 6, lane = threadIdx.x & 63;
  int i = blockIdx.x * 4 + wave;
  if (i >= N) return;
  int s = x_idx[i];
  float4 v = *(const float4*)(emb + (size_t)s * 256 + lane * 4);
  bf16x4 o = { (__bf16)v.x, (__bf16)v.y, (__bf16)v.z, (__bf16)v.w };
  *(bf16x4*)(xbase + (size_t)i * ROWB + lane * 8) = o;
}

// ---- mean aggregation -----------------------------------------------------
// Wave per node; 2x32-lane halves read DIFFERENT src rows at 16B/lane
// (dwordx4). 8 edges/iter, 4 loads in flight. shfl_down(32) combine.
// Perf-equal across MLP 1/2/4 variants -> L2-fill throughput ceiling.

__global__ void sage_agg(const char* __restrict__ srcbase,  // row r: srcbase + r*ROWB, 256 bf16
                         char* __restrict__ dstbase,        // node i: dstbase + i*ROWB, 256 bf16
                         const int* __restrict__ csr, const int* __restrict__ cnt,
                         const int* __restrict__ offs, int N) {
  int wave = threadIdx.x >> 6, lane = threadIdx.x & 63;
  int i = blockIdx.x * 4 + wave;
  if (i >= N) return;
  int deg = cnt[i];
  const int* lp = csr + offs[i];
  int half = lane >> 5, l5 = lane & 31;
  const char* sb = srcbase + l5 * 16;

  f32x8 acc = (f32x8)0.f;
  int g8 = deg >> 3;
  for (int t = 0; t < g8; ++t) {  // 8 edges per iteration (4 per half)
    const int* p = lp + t * 8 + half;
    int s0 = p[0], s1 = p[2], s2 = p[4], s3 = p[6];
    bf16x8 v0 = *(const bf16x8*)(sb + (size_t)s0 * ROWB);
    bf16x8 v1 = *(const bf16x8*)(sb + (size_t)s1 * ROWB);
    bf16x8 v2 = *(const bf16x8*)(sb + (size_t)s2 * ROWB);
    bf16x8 v3 = *(const bf16x8*)(sb + (size_t)s3 * ROWB);
#pragma unroll
    for (int k = 0; k < 8; ++k)
      acc[k] += ((float)v0[k] + (float)v1[k]) + ((float)v2[k] + (float)v3[k]);
  }
  int base = g8 * 8;
  int rem = deg & 7;
  int rp = rem >> 1;
  for (int u = 0; u < rp; ++u) {
    int r0 = lp[base + 2 * u + half];
    bf16x8 v0 = *(const bf16x8*)(sb + (size_t)r0 * ROWB);
#pragma unroll
    for (int k = 0; k < 8; ++k) acc[k] += (float)v0[k];
  }
  if ((rem & 1) && half == 0) {
    int r0 = lp[deg - 1];
    bf16x8 v0 = *(const bf16x8*)(sb + (size_t)r0 * ROWB);
#pragma unroll
    for (int k = 0; k < 8; ++k) acc[k] += (float)v0[k];
  }

  float inv = 1.0f / (float)(deg > 0 ? deg : 1);
  bf16x8 o;
#pragma unroll
  for (int k = 0; k < 8; ++k) {
    float s = acc[k] + __shfl_down(acc[k], 32);
    o[k] = (__bf16)(s * inv);
  }
  if (half == 0)
    *(bf16x8*)(dstbase + (size_t)i * ROWB + l5 * 16) = o;
}

// ---- fused GEMM: out[M,256] = A[M,512] @ Wcat[512,256] + bias -------------
// R9: BM=128, BN=256 (full), BK=32, 256 threads = 4 waves (2m x 2n),
// wave tile 64x128 -> per wave-kk: 12 ds_read_b128 (144cy) vs 32 MFMA
// (160cy) = MFMA-limited (old 32x128 tile: 10 reads vs 16 MFMA, LDS-bound).

template <int OUT_F32>
__global__ __launch_bounds__(256) void gemm_sage(const char* __restrict__ Abase,
                                                 const __bf16* __restrict__ Wt,
                                                 const float* __restrict__ bias,
                                                 char* __restrict__ outbase, int M) {
  __shared__ __align__(16) char lds[49152];  // 2 bufs x (A 8KB + B 16KB)
  const int tid = threadIdx.x;
  const int wave = tid >> 6, lane = tid & 63;
  const int r = lane & 15, q = lane >> 4;
  const int wm = wave >> 1, wn = wave & 1;
  const int row0 = blockIdx.x * 128;

  f32x4 acc[4][8];
#pragma unroll
  for (int t = 0; t < 4; ++t)
#pragma unroll
    for (int u = 0; u < 8; ++u) acc[t][u] = (f32x4)0.f;

  auto stage = [&](int kk, int buf) {
    char* lbase = lds + buf * 24576;
    // A: 8 x 1KB chunks (16 rows x 32 cols each); each thread issues 2
#pragma unroll
    for (int i = 0; i < 2; ++i) {
      int h = wave * 2 + i;  // 0..7
      int rowA = row0 + h * 16 + r;
      rowA = rowA < M ? rowA : M - 1;  // clamp: garbage rows masked at store
      async_copy16(lbase + h * 1024 + lane * 16,
                   Abase + (size_t)rowA * ROWB + (size_t)(kk * 32 + q * 8) * 2);
    }
    // B: 16 x 1KB chunks (16 cols x 32 k each); each thread issues 4
#pragma unroll
    for (int i = 0; i < 4; ++i) {
      int h = wave * 4 + i;  // 0..15
      async_copy16(lbase + 8192 + h * 1024 + lane * 16,
                   (const char*)Wt + ((size_t)(h * 16 + r) * 512 + kk * 32 + q * 8) * 2);
    }
  };

  stage(0, 0);
  for (int kk = 0; kk < 16; ++kk) {
    __syncthreads();  // compiler drains vmcnt before s_barrier -> staging done
    if (kk < 15) stage(kk + 1, (kk + 1) & 1);
    const char* lbase = lds + (kk & 1) * 24576;
    bf16x8 a[4];
#pragma unroll
    for (int t = 0; t < 4; ++t)
      a[t] = *(const bf16x8*)(lbase + (wm * 4 + t) * 1024 + lane * 16);
#pragma unroll
    for (int u = 0; u < 8; ++u) {
      bf16x8 b = *(const bf16x8*)(lbase + 8192 + (wn * 8 + u) * 1024 + lane * 16);
#pragma unroll
      for (int t = 0; t < 4; ++t)
        acc[t][u] = __builtin_amdgcn_mfma_f32_16x16x32_bf16(a[t], b, acc[t][u], 0, 0, 0);
    }
  }

  // epilogue. All global A reads drained at the kk=15 barrier, so in-place
  // fp32 overwrite of this block's own rows (sole owner, BN=256) is safe.
#pragma unroll
  for (int t = 0; t < 4; ++t) {
    int rbase = row0 + wm * 64 + t * 16 + q * 4;
#pragma unroll
    for (int u = 0; u < 8; ++u) {
      int col = wn * 128 + u * 16 + r;
      float bv = bias[col];
#pragma unroll
      for (int j = 0; j < 4; ++j) {
        int row = rbase + j;
        if (row < M) {
          float v = acc[t][u][j] + bv;
          if (OUT_F32)
            *(float*)(outbase + (size_t)row * ROWB + col * 4) = v;
          else
            *(__bf16*)(outbase + (size_t)row * ROWB + 512 + col * 2) = (__bf16)v;
        }
      }
    }
  }
}

// ---- final index gathers --------------------------------------------------

__global__ void gather_out_kernel(const float* __restrict__ x2, const int* __restrict__ drug,
                                  const int* __restrict__ se, float* __restrict__ out,
                                  int nd, int ns) {
  int wave = threadIdx.x >> 6, lane = threadIdx.x & 63;
  int ro = blockIdx.x * 4 + wave;
  if (ro >= nd + ns) return;
  int node = (ro < nd) ? drug[ro] : se[ro - nd];
  float4 v = *(const float4*)(x2 + (size_t)node * 256 + lane * 4);
  *(float4*)(out + (size_t)ro * 256 + lane * 4) = v;
}

// ---------------------------------------------------------------------------

extern "C" void kernel_launch(void* const* d_in, const int* in_sizes, int n_in,
                              void* d_out, int out_size, void* d_ws, size_t ws_size,
                              hipStream_t stream) {
  const float* emb  = (const float*)d_in[0];
  const float* W1l  = (const float*)d_in[1];
  const float* b1l  = (const float*)d_in[2];
  const float* W1r  = (const float*)d_in[3];
  const float* W2l  = (const float*)d_in[4];
  const float* b2l  = (const float*)d_in[5];
  const float* W2r  = (const float*)d_in[6];
  const int* x_idx  = (const int*)d_in[7];
  const int* edge   = (const int*)d_in[8];
  const int* drug   = (const int*)d_in[9];
  const int* se     = (const int*)d_in[10];

  const int N = in_sizes[7];       // 100000
  const int E = in_sizes[8] / 2;   // 1600000
  const int nd = in_sizes[9], ns = in_sizes[10];
  const int* esrc = edge;
  const int* edst = edge + E;
  const int NBUK = (N + 63) >> 6;  // 1563 (<= MAXBUK)
  const int chunk = (E + NPART - 1) / NPART;

  // persistent workspace carve (~110 MB)
  char* ws = (char*)d_ws;
  size_t off = 0;
  char* xA1 = ws;                       off += (size_t)((N + 127) & ~127) * ROWB;
  __bf16* Wt1 = (__bf16*)(ws + off);    off += 512 * 256 * 2;
  __bf16* Wt2 = (__bf16*)(ws + off);    off += 512 * 256 * 2;
  int* cnt  = (int*)(ws + off);         off += ((size_t)N * 4 + 255) & ~(size_t)255;
  int* offs = (int*)(ws + off);         off += ((size_t)N * 4 + 255) & ~(size_t)255;
  int* csr  = (int*)(ws + off);         off += ((size_t)E * 4 + 255) & ~(size_t)255;
  // transient arrays overlay xA1 (all dead before gather_x writes xA1):
  int* ebuf = (int*)xA1;                         // E ints (6.4 MB)
  int* hmat = (int*)(xA1 + (8u << 20));          // NPART*NBUK ints (~1.6 MB)
  int* btot = (int*)(xA1 + (16u << 20));         // NBUK ints
  int* boff = (int*)(xA1 + (16u << 20) + 16384); // NBUK ints

  // d_out carve: [drug nd*256 | se ns*256 | x2 N*256] fp32
  float* outp = (float*)d_out;
  float* x2 = outp + (size_t)(nd + ns) * 256;
  char* scratch2 = (char*)x2;  // rows of 1KB: [mean2 bf16 | x1 bf16] -> x2 fp32

  const int QB = (N + 3) / 4;
  const int GB = (N + 127) / 128;   // gemm grid, BM=128

  prep_w_kernel<<<(2 * 131072) / 256, 256, 0, stream>>>(W1l, W1r, W2l, W2r, Wt1, Wt2);

  // CSR build, deterministic (no global atomics)
  bin_count<<<NPART, 256, 0, stream>>>(edst, hmat, E, chunk, NBUK);
  col_scan<<<NBUK, NPART, 0, stream>>>(hmat, btot, NBUK);
  bucket_scan<<<1, 1024, 0, stream>>>(btot, boff, NBUK);
  part_write<<<NPART, 256, 0, stream>>>(esrc, edst, hmat, boff, ebuf, E, chunk, NBUK);
  node_hist_scan<<<NBUK, 256, 0, stream>>>(ebuf, boff, btot, cnt, offs, N);
  csr_write<<<NBUK, 256, 0, stream>>>(ebuf, boff, btot, offs, csr, N);

  gather_x_kernel<<<QB, 256, 0, stream>>>(emb, x_idx, xA1 + 512, N);
  // layer 1
  sage_agg<<<QB, 256, 0, stream>>>(xA1 + 512, xA1, csr, cnt, offs, N);
  gemm_sage<0><<<GB, 256, 0, stream>>>(xA1, Wt1, b1l, scratch2, N);
  // layer 2
  sage_agg<<<QB, 256, 0, stream>>>(scratch2 + 512, scratch2, csr, cnt, offs, N);
  gemm_sage<1><<<GB, 256, 0, stream>>>(scratch2, Wt2, b2l, scratch2, N);

  gather_out_kernel<<<(nd + ns + 3) / 4, 256, 0, stream>>>(x2, drug, se, outp, nd, ns);
}

// Round 9
// 637.051 us; speedup vs baseline: 1.0829x; 1.0062x over previous
//
#include <hip/hip_runtime.h>
#include <hip/hip_bf16.h>

// ---------------------------------------------------------------------------
// 2-layer GraphSAGE (mean aggr) on gfx950.
// R9 (this round): revert R8 fusion (fused=215us/layer vs split 111+94;
// 2 blocks/CU starved the gather's TLP -> BW 3.9->2.4 TB/s). Keep
// node_hist_scan fusion. NEW: gemm_sage BM=128, wave tile 64x128 (acc[4][8],
// 4 waves): halves LDS reads per MFMA (12 ds_read vs 32 MFMA per wave-kk,
// was 10 vs 16) -> MFMA-limited instead of LDS-bound. Predict G 94->~55us.
// R5-R7: sage_agg is at a ~3.9 TB/s L2-fill throughput ceiling (379 MB
// FETCH, flat across MLP 1/2/4) -> left as the proven R6 form.
// CSR build deterministic (R3): bin_count -> col_scan -> bucket_scan ->
// part_write -> node_hist_scan -> csr_write. No contended global atomics.
// ---------------------------------------------------------------------------

typedef __bf16 bf16x8 __attribute__((ext_vector_type(8)));
typedef __bf16 bf16x4 __attribute__((ext_vector_type(4)));
typedef float  f32x4  __attribute__((ext_vector_type(4)));
typedef float  f32x8  __attribute__((ext_vector_type(8)));

#define ROWB 1024   // bytes per A row: 512 bf16 (K = 512 = [mean | x])
#define NPART 256   // partition blocks
#define MAXBUK 2048 // bucket capacity bound (N<=131072)

__device__ __forceinline__ void async_copy16(void* lds_dst, const void* g_src) {
  __builtin_amdgcn_global_load_lds(
      (const __attribute__((address_space(1))) void*)g_src,
      (__attribute__((address_space(3))) void*)lds_dst, 16, 0, 0);
}

// ---- CSR build ------------------------------------------------------------

// block p: LDS histogram of dst>>6 over its chunk -> hmat[p][:]
__global__ void bin_count(const int* __restrict__ dst, int* __restrict__ hmat,
                          int E, int chunk, int nbuk) {
  __shared__ int lh[MAXBUK];
  int p = blockIdx.x, tid = threadIdx.x;
  for (int i = tid; i < nbuk; i += 256) lh[i] = 0;
  __syncthreads();
  int base = p * chunk, end = min(base + chunk, E);
  for (int e = base + tid; e < end; e += 256) atomicAdd(&lh[dst[e] >> 6], 1);
  __syncthreads();
  for (int i = tid; i < nbuk; i += 256) hmat[p * nbuk + i] = lh[i];
}

// block b: exclusive scan of hmat[0..NPART-1][b]; btot[b] = total
__global__ void col_scan(int* __restrict__ hmat, int* __restrict__ btot, int nbuk) {
  __shared__ int s[NPART];
  int b = blockIdx.x, t = threadIdx.x;  // NPART threads
  int v = hmat[t * nbuk + b];
  s[t] = v; __syncthreads();
  for (int d = 1; d < NPART; d <<= 1) {
    int add = (t >= d) ? s[t - d] : 0;
    __syncthreads();
    s[t] += add;
    __syncthreads();
  }
  hmat[t * nbuk + b] = s[t] - v;  // exclusive within bucket
  if (t == NPART - 1) btot[b] = s[t];
}

// single block, 1024 threads, nb <= 2048: exclusive scan btot -> boff
__global__ void bucket_scan(const int* __restrict__ btot, int* __restrict__ boff, int nb) {
  __shared__ int s[2048];
  int t = threadIdx.x;
  for (int i = t; i < 2048; i += 1024) s[i] = (i < nb) ? btot[i] : 0;
  __syncthreads();
  for (int d = 1; d < 2048; d <<= 1) {
    int v0 = (t >= d) ? s[t - d] : 0;
    int v1 = (t + 1024 >= d) ? s[t + 1024 - d] : 0;
    __syncthreads();
    s[t] += v0; s[t + 1024] += v1;
    __syncthreads();
  }
  for (int i = t; i < nb; i += 1024) boff[i] = s[i] - btot[i];
}

// block p: write its chunk's edges into disjoint per-bucket windows.
// entry = src | ((dst&63) << 18)   (src < 2^18)
__global__ void part_write(const int* __restrict__ src, const int* __restrict__ dst,
                           const int* __restrict__ hmat, const int* __restrict__ boff,
                           int* __restrict__ ebuf, int E, int chunk, int nbuk) {
  __shared__ int cur[MAXBUK];
  int p = blockIdx.x, tid = threadIdx.x;
  for (int i = tid; i < nbuk; i += 256) cur[i] = hmat[p * nbuk + i] + boff[i];
  __syncthreads();
  int base = p * chunk, end = min(base + chunk, E);
  for (int e = base + tid; e < end; e += 256) {
    int d = dst[e];
    int pos = atomicAdd(&cur[d >> 6], 1);  // LDS atomic, low contention
    ebuf[pos] = src[e] | ((d & 63) << 18);
  }
}

// block b: degree histogram of its 64 nodes + in-bucket exclusive scan ->
// cnt[node], offs[node] = boff[b] + scan. Replaces node_hist + 3 scan kernels.
__global__ void node_hist_scan(const int* __restrict__ ebuf, const int* __restrict__ boff,
                               const int* __restrict__ btot, int* __restrict__ cnt,
                               int* __restrict__ offs, int N) {
  __shared__ int lh[64];
  int b = blockIdx.x, tid = threadIdx.x;
  if (tid < 64) lh[tid] = 0;
  __syncthreads();
  int s0 = boff[b], s1 = s0 + btot[b];
  for (int i = s0 + tid; i < s1; i += 256) atomicAdd(&lh[ebuf[i] >> 18], 1);
  __syncthreads();
  if (tid < 64) {  // wave 0: 64-wide inclusive shfl scan
    int v = lh[tid];
    int x = v;
#pragma unroll
    for (int d = 1; d < 64; d <<= 1) {
      int y = __shfl_up(x, d);
      if (tid >= d) x += y;
    }
    int node = b * 64 + tid;
    if (node < N) { cnt[node] = v; offs[node] = s0 + x - v; }
  }
}

// block b: place its bucket's edges into csr via LDS cursors (4KB window)
__global__ void csr_write(const int* __restrict__ ebuf, const int* __restrict__ boff,
                          const int* __restrict__ btot, const int* __restrict__ offs,
                          int* __restrict__ csr, int N) {
  __shared__ int cur[64];
  int b = blockIdx.x, tid = threadIdx.x;
  int node = b * 64 + tid;
  if (tid < 64) cur[tid] = (node < N) ? offs[node] : 0;
  __syncthreads();
  int s0 = boff[b], s1 = s0 + btot[b];
  for (int i = s0 + tid; i < s1; i += 256) {
    int e = ebuf[i];
    int p = atomicAdd(&cur[e >> 18], 1);
    csr[p] = e & 0x3FFFF;
  }
}

// ---- feature prep ---------------------------------------------------------

// Wt[n][k] = bf16( k<256 ? Wl[k][n] : Wr[k-256][n] ), row-major [256][512]
__global__ void prep_w_kernel(const float* __restrict__ W1l, const float* __restrict__ W1r,
                              const float* __restrict__ W2l, const float* __restrict__ W2r,
                              __bf16* __restrict__ Wt1, __bf16* __restrict__ Wt2) {
  int idx = blockIdx.x * 256 + threadIdx.x;  // 0 .. 2*131072-1
  int which = idx >> 17;
  int j = idx & 131071;
  int n = j >> 9, k = j & 511;
  const float* Wl = which ? W2l : W1l;
  const float* Wr = which ? W2r : W1r;
  float v = (k < 256) ? Wl[k * 256 + n] : Wr[(k - 256) * 256 + n];
  (which ? Wt2 : Wt1)[j] = (__bf16)v;
}

// x-half gather: xbase points at (row stride ROWB) destination of the x slot
__global__ void gather_x_kernel(const float* __restrict__ emb, const int* __restrict__ x_idx,
                                char* __restrict__ xbase, int N) {
  int wave = threadIdx.x >> 6, lane = threadIdx.x & 63;
  int i = blockIdx.x * 4 + wave;
  if (i >= N) return;
  int s = x_idx[i];
  float4 v = *(const float4*)(emb + (size_t)s * 256 + lane * 4);
  bf16x4 o = { (__bf16)v.x, (__bf16)v.y, (__bf16)v.z, (__bf16)v.w };
  *(bf16x4*)(xbase + (size_t)i * ROWB + lane * 8) = o;
}

// ---- mean aggregation -----------------------------------------------------
// Wave per node; 2x32-lane halves read DIFFERENT src rows at 16B/lane
// (dwordx4). 8 edges/iter, 4 loads in flight. shfl_down(32) combine.
// Perf-equal across MLP 1/2/4 variants -> L2-fill throughput ceiling.

__global__ void sage_agg(const char* __restrict__ srcbase,  // row r: srcbase + r*ROWB, 256 bf16
                         char* __restrict__ dstbase,        // node i: dstbase + i*ROWB, 256 bf16
                         const int* __restrict__ csr, const int* __restrict__ cnt,
                         const int* __restrict__ offs, int N) {
  int wave = threadIdx.x >> 6, lane = threadIdx.x & 63;
  int i = blockIdx.x * 4 + wave;
  if (i >= N) return;
  int deg = cnt[i];
  const int* lp = csr + offs[i];
  int half = lane >> 5, l5 = lane & 31;
  const char* sb = srcbase + l5 * 16;

  f32x8 acc = (f32x8)0.f;
  int g8 = deg >> 3;
  for (int t = 0; t < g8; ++t) {  // 8 edges per iteration (4 per half)
    const int* p = lp + t * 8 + half;
    int s0 = p[0], s1 = p[2], s2 = p[4], s3 = p[6];
    bf16x8 v0 = *(const bf16x8*)(sb + (size_t)s0 * ROWB);
    bf16x8 v1 = *(const bf16x8*)(sb + (size_t)s1 * ROWB);
    bf16x8 v2 = *(const bf16x8*)(sb + (size_t)s2 * ROWB);
    bf16x8 v3 = *(const bf16x8*)(sb + (size_t)s3 * ROWB);
#pragma unroll
    for (int k = 0; k < 8; ++k)
      acc[k] += ((float)v0[k] + (float)v1[k]) + ((float)v2[k] + (float)v3[k]);
  }
  int base = g8 * 8;
  int rem = deg & 7;
  int rp = rem >> 1;
  for (int u = 0; u < rp; ++u) {
    int r0 = lp[base + 2 * u + half];
    bf16x8 v0 = *(const bf16x8*)(sb + (size_t)r0 * ROWB);
#pragma unroll
    for (int k = 0; k < 8; ++k) acc[k] += (float)v0[k];
  }
  if ((rem & 1) && half == 0) {
    int r0 = lp[deg - 1];
    bf16x8 v0 = *(const bf16x8*)(sb + (size_t)r0 * ROWB);
#pragma unroll
    for (int k = 0; k < 8; ++k) acc[k] += (float)v0[k];
  }

  float inv = 1.0f / (float)(deg > 0 ? deg : 1);
  bf16x8 o;
#pragma unroll
  for (int k = 0; k < 8; ++k) {
    float s = acc[k] + __shfl_down(acc[k], 32);
    o[k] = (__bf16)(s * inv);
  }
  if (half == 0)
    *(bf16x8*)(dstbase + (size_t)i * ROWB + l5 * 16) = o;
}

// ---- fused GEMM: out[M,256] = A[M,512] @ Wcat[512,256] + bias -------------
// R9: BM=128, BN=256 (full), BK=32, 256 threads = 4 waves (2m x 2n),
// wave tile 64x128 -> per wave-kk: 12 ds_read_b128 (144cy) vs 32 MFMA
// (160cy) = MFMA-limited (old 32x128 tile: 10 reads vs 16 MFMA, LDS-bound).

template <int OUT_F32>
__global__ __launch_bounds__(256) void gemm_sage(const char* __restrict__ Abase,
                                                 const __bf16* __restrict__ Wt,
                                                 const float* __restrict__ bias,
                                                 char* __restrict__ outbase, int M) {
  __shared__ __align__(16) char lds[49152];  // 2 bufs x (A 8KB + B 16KB)
  const int tid = threadIdx.x;
  const int wave = tid >> 6, lane = tid & 63;
  const int r = lane & 15, q = lane >> 4;
  const int wm = wave >> 1, wn = wave & 1;
  const int row0 = blockIdx.x * 128;

  f32x4 acc[4][8];
#pragma unroll
  for (int t = 0; t < 4; ++t)
#pragma unroll
    for (int u = 0; u < 8; ++u) acc[t][u] = (f32x4)0.f;

  auto stage = [&](int kk, int buf) {
    char* lbase = lds + buf * 24576;
    // A: 8 x 1KB chunks (16 rows x 32 cols each); each thread issues 2
#pragma unroll
    for (int i = 0; i < 2; ++i) {
      int h = wave * 2 + i;  // 0..7
      int rowA = row0 + h * 16 + r;
      rowA = rowA < M ? rowA : M - 1;  // clamp: garbage rows masked at store
      async_copy16(lbase + h * 1024 + lane * 16,
                   Abase + (size_t)rowA * ROWB + (size_t)(kk * 32 + q * 8) * 2);
    }
    // B: 16 x 1KB chunks (16 cols x 32 k each); each thread issues 4
#pragma unroll
    for (int i = 0; i < 4; ++i) {
      int h = wave * 4 + i;  // 0..15
      async_copy16(lbase + 8192 + h * 1024 + lane * 16,
                   (const char*)Wt + ((size_t)(h * 16 + r) * 512 + kk * 32 + q * 8) * 2);
    }
  };

  stage(0, 0);
  for (int kk = 0; kk < 16; ++kk) {
    __syncthreads();  // compiler drains vmcnt before s_barrier -> staging done
    if (kk < 15) stage(kk + 1, (kk + 1) & 1);
    const char* lbase = lds + (kk & 1) * 24576;
    bf16x8 a[4];
#pragma unroll
    for (int t = 0; t < 4; ++t)
      a[t] = *(const bf16x8*)(lbase + (wm * 4 + t) * 1024 + lane * 16);
#pragma unroll
    for (int u = 0; u < 8; ++u) {
      bf16x8 b = *(const bf16x8*)(lbase + 8192 + (wn * 8 + u) * 1024 + lane * 16);
#pragma unroll
      for (int t = 0; t < 4; ++t)
        acc[t][u] = __builtin_amdgcn_mfma_f32_16x16x32_bf16(a[t], b, acc[t][u], 0, 0, 0);
    }
  }

  // epilogue. All global A reads drained at the kk=15 barrier, so in-place
  // fp32 overwrite of this block's own rows (sole owner, BN=256) is safe.
#pragma unroll
  for (int t = 0; t < 4; ++t) {
    int rbase = row0 + wm * 64 + t * 16 + q * 4;
#pragma unroll
    for (int u = 0; u < 8; ++u) {
      int col = wn * 128 + u * 16 + r;
      float bv = bias[col];
#pragma unroll
      for (int j = 0; j < 4; ++j) {
        int row = rbase + j;
        if (row < M) {
          float v = acc[t][u][j] + bv;
          if (OUT_F32)
            *(float*)(outbase + (size_t)row * ROWB + col * 4) = v;
          else
            *(__bf16*)(outbase + (size_t)row * ROWB + 512 + col * 2) = (__bf16)v;
        }
      }
    }
  }
}

// ---- final index gathers --------------------------------------------------

__global__ void gather_out_kernel(const float* __restrict__ x2, const int* __restrict__ drug,
                                  const int* __restrict__ se, float* __restrict__ out,
                                  int nd, int ns) {
  int wave = threadIdx.x >> 6, lane = threadIdx.x & 63;
  int ro = blockIdx.x * 4 + wave;
  if (ro >= nd + ns) return;
  int node = (ro < nd) ? drug[ro] : se[ro - nd];
  float4 v = *(const float4*)(x2 + (size_t)node * 256 + lane * 4);
  *(float4*)(out + (size_t)ro * 256 + lane * 4) = v;
}

// ---------------------------------------------------------------------------

extern "C" void kernel_launch(void* const* d_in, const int* in_sizes, int n_in,
                              void* d_out, int out_size, void* d_ws, size_t ws_size,
                              hipStream_t stream) {
  const float* emb  = (const float*)d_in[0];
  const float* W1l  = (const float*)d_in[1];
  const float* b1l  = (const float*)d_in[2];
  const float* W1r  = (const float*)d_in[3];
  const float* W2l  = (const float*)d_in[4];
  const float* b2l  = (const float*)d_in[5];
  const float* W2r  = (const float*)d_in[6];
  const int* x_idx  = (const int*)d_in[7];
  const int* edge   = (const int*)d_in[8];
  const int* drug   = (const int*)d_in[9];
  const int* se     = (const int*)d_in[10];

  const int N = in_sizes[7];       // 100000
  const int E = in_sizes[8] / 2;   // 1600000
  const int nd = in_sizes[9], ns = in_sizes[10];
  const int* esrc = edge;
  const int* edst = edge + E;
  const int NBUK = (N + 63) >> 6;  // 1563 (<= MAXBUK)
  const int chunk = (E + NPART - 1) / NPART;

  // persistent workspace carve (~110 MB)
  char* ws = (char*)d_ws;
  size_t off = 0;
  char* xA1 = ws;                       off += (size_t)((N + 127) & ~127) * ROWB;
  __bf16* Wt1 = (__bf16*)(ws + off);    off += 512 * 256 * 2;
  __bf16* Wt2 = (__bf16*)(ws + off);    off += 512 * 256 * 2;
  int* cnt  = (int*)(ws + off);         off += ((size_t)N * 4 + 255) & ~(size_t)255;
  int* offs = (int*)(ws + off);         off += ((size_t)N * 4 + 255) & ~(size_t)255;
  int* csr  = (int*)(ws + off);         off += ((size_t)E * 4 + 255) & ~(size_t)255;
  // transient arrays overlay xA1 (all dead before gather_x writes xA1):
  int* ebuf = (int*)xA1;                         // E ints (6.4 MB)
  int* hmat = (int*)(xA1 + (8u << 20));          // NPART*NBUK ints (~1.6 MB)
  int* btot = (int*)(xA1 + (16u << 20));         // NBUK ints
  int* boff = (int*)(xA1 + (16u << 20) + 16384); // NBUK ints

  // d_out carve: [drug nd*256 | se ns*256 | x2 N*256] fp32
  float* outp = (float*)d_out;
  float* x2 = outp + (size_t)(nd + ns) * 256;
  char* scratch2 = (char*)x2;  // rows of 1KB: [mean2 bf16 | x1 bf16] -> x2 fp32

  const int QB = (N + 3) / 4;
  const int GB = (N + 127) / 128;   // gemm grid, BM=128

  prep_w_kernel<<<(2 * 131072) / 256, 256, 0, stream>>>(W1l, W1r, W2l, W2r, Wt1, Wt2);

  // CSR build, deterministic (no global atomics)
  bin_count<<<NPART, 256, 0, stream>>>(edst, hmat, E, chunk, NBUK);
  col_scan<<<NBUK, NPART, 0, stream>>>(hmat, btot, NBUK);
  bucket_scan<<<1, 1024, 0, stream>>>(btot, boff, NBUK);
  part_write<<<NPART, 256, 0, stream>>>(esrc, edst, hmat, boff, ebuf, E, chunk, NBUK);
  node_hist_scan<<<NBUK, 256, 0, stream>>>(ebuf, boff, btot, cnt, offs, N);
  csr_write<<<NBUK, 256, 0, stream>>>(ebuf, boff, btot, offs, csr, N);

  gather_x_kernel<<<QB, 256, 0, stream>>>(emb, x_idx, xA1 + 512, N);
  // layer 1
  sage_agg<<<QB, 256, 0, stream>>>(xA1 + 512, xA1, csr, cnt, offs, N);
  gemm_sage<0><<<GB, 256, 0, stream>>>(xA1, Wt1, b1l, scratch2, N);
  // layer 2
  sage_agg<<<QB, 256, 0, stream>>>(scratch2 + 512, scratch2, csr, cnt, offs, N);
  gemm_sage<1><<<GB, 256, 0, stream>>>(scratch2, Wt2, b2l, scratch2, N);

  gather_out_kernel<<<(nd + ns + 3) / 4, 256, 0, stream>>>(x2, drug, se, outp, nd, ns);
}